// Round 1
// baseline (277.764 us; speedup 1.0000x reference)
//
#include <hip/hip_runtime.h>
#include <math.h>

// Problem constants (match reference)
constexpr int NUM_HEADS    = 32;
constexpr int NUM_KV_HEADS = 8;
constexpr int HEAD_SIZE    = 128;
constexpr int T            = 16384;
constexpr int NUM_SLOTS    = 32768;
constexpr int QD = NUM_HEADS * HEAD_SIZE;     // 4096 floats per token
constexpr int KD = NUM_KV_HEADS * HEAD_SIZE;  // 1024 floats per token
constexpr int HALF = HEAD_SIZE / 2;           // 64

// Output layout (flat float offsets in d_out, reference return order)
constexpr size_t Q_OUT  = 0;
constexpr size_t K_OUT  = (size_t)T * QD;              //  67,108,864
constexpr size_t V_OUT  = K_OUT + (size_t)T * KD;      //  83,886,080
constexpr size_t KC_OUT = V_OUT + (size_t)T * KD;      // 100,663,296
constexpr size_t VC_OUT = KC_OUT + (size_t)NUM_SLOTS * KD; // 134,217,728

__device__ __forceinline__ void rope4(const float4& a, const float4& b,
                                      const float* cs, const float* sn, int j0,
                                      float4& o1, float4& o2) {
    o1.x = a.x * cs[j0 + 0] - b.x * sn[j0 + 0];
    o1.y = a.y * cs[j0 + 1] - b.y * sn[j0 + 1];
    o1.z = a.z * cs[j0 + 2] - b.z * sn[j0 + 2];
    o1.w = a.w * cs[j0 + 3] - b.w * sn[j0 + 3];
    o2.x = b.x * cs[j0 + 0] + a.x * sn[j0 + 0];
    o2.y = b.y * cs[j0 + 1] + a.y * sn[j0 + 1];
    o2.z = b.z * cs[j0 + 2] + a.z * sn[j0 + 2];
    o2.w = b.w * cs[j0 + 3] + a.w * sn[j0 + 3];
}

__global__ __launch_bounds__(256) void rope_kv_kernel(
    const float* __restrict__ q, const float* __restrict__ k,
    const float* __restrict__ v,
    const int* __restrict__ positions, const int* __restrict__ slot_mapping,
    float* __restrict__ out)
{
    const int tok = blockIdx.x;
    const int tid = threadIdx.x;

    __shared__ float cs[HALF];
    __shared__ float sn[HALF];

    const int pos  = positions[tok];
    const int slot = slot_mapping[tok];

    if (tid < HALF) {
        // inv_freq[j] = 10000^(-2j/128), computed in double for accuracy.
        const double inv = exp(-(double)(2 * tid) * (log(10000.0) / 128.0));
        const float freq = (float)((double)pos * inv);
        float s, c;
        sincosf(freq, &s, &c);
        cs[tid] = c;
        sn[tid] = s;
    }
    __syncthreads();

    // ---- Q rope: 32 heads x 16 pair-quads = 512 pair-quads ----
    {
        const float4* qrow = (const float4*)(q + (size_t)tok * QD);
        float4*       orow = (float4*)(out + Q_OUT + (size_t)tok * QD);
        #pragma unroll
        for (int i = 0; i < 2; ++i) {
            const int p    = i * 256 + tid;   // 0..511
            const int head = p >> 4;
            const int jq   = p & 15;
            const int j0   = jq * 4;
            const float4 a = qrow[head * 32 + jq];
            const float4 b = qrow[head * 32 + 16 + jq];
            float4 o1, o2;
            rope4(a, b, cs, sn, j0, o1, o2);
            orow[head * 32 + jq]      = o1;
            orow[head * 32 + 16 + jq] = o2;
        }
    }

    // ---- K rope + scatter into k_cache_new: 8 heads x 16 pair-quads = 128 ----
    if (tid < 128) {
        const int head = tid >> 4;
        const int jq   = tid & 15;
        const int j0   = jq * 4;
        const float4* krow = (const float4*)(k + (size_t)tok * KD);
        const float4 a = krow[head * 32 + jq];
        const float4 b = krow[head * 32 + 16 + jq];
        float4 o1, o2;
        rope4(a, b, cs, sn, j0, o1, o2);
        float4* korow = (float4*)(out + K_OUT + (size_t)tok * KD);
        korow[head * 32 + jq]      = o1;
        korow[head * 32 + 16 + jq] = o2;
        float4* kcrow = (float4*)(out + KC_OUT + (size_t)slot * KD);
        kcrow[head * 32 + jq]      = o1;
        kcrow[head * 32 + 16 + jq] = o2;
    }

    // ---- V passthrough + scatter into v_cache_new: 256 float4 ----
    {
        const float4* vrow = (const float4*)(v + (size_t)tok * KD);
        const float4 val = vrow[tid];
        ((float4*)(out + V_OUT  + (size_t)tok  * KD))[tid] = val;
        ((float4*)(out + VC_OUT + (size_t)slot * KD))[tid] = val;
    }
}

extern "C" void kernel_launch(void* const* d_in, const int* in_sizes, int n_in,
                              void* d_out, int out_size, void* d_ws, size_t ws_size,
                              hipStream_t stream) {
    const float* q   = (const float*)d_in[0];
    const float* k   = (const float*)d_in[1];
    const float* v   = (const float*)d_in[2];
    const int* positions    = (const int*)d_in[3];
    const int* slot_mapping = (const int*)d_in[4];
    const float* k_cache = (const float*)d_in[5];
    const float* v_cache = (const float*)d_in[6];
    float* out = (float*)d_out;

    // Base cache copies (scattered rows overwritten by the kernel afterwards,
    // ordered on the same stream).
    const size_t cache_bytes = (size_t)NUM_SLOTS * KD * sizeof(float);
    hipMemcpyAsync(out + KC_OUT, k_cache, cache_bytes, hipMemcpyDeviceToDevice, stream);
    hipMemcpyAsync(out + VC_OUT, v_cache, cache_bytes, hipMemcpyDeviceToDevice, stream);

    rope_kv_kernel<<<T, 256, 0, stream>>>(q, k, v, positions, slot_mapping, out);
}

// Round 2
// 240.542 us; speedup vs baseline: 1.1547x; 1.1547x over previous
//
#include <hip/hip_runtime.h>
#include <math.h>

// Problem constants (match reference)
constexpr int NUM_HEADS    = 32;
constexpr int NUM_KV_HEADS = 8;
constexpr int HEAD_SIZE    = 128;
constexpr int T            = 16384;
constexpr int NUM_SLOTS    = 32768;
constexpr int QD = NUM_HEADS * HEAD_SIZE;     // 4096 floats per token
constexpr int KD = NUM_KV_HEADS * HEAD_SIZE;  // 1024 floats per token
constexpr int HALF = HEAD_SIZE / 2;           // 64

// Output layout (flat float offsets in d_out, reference return order)
constexpr size_t Q_OUT  = 0;
constexpr size_t K_OUT  = (size_t)T * QD;                  //  67,108,864
constexpr size_t V_OUT  = K_OUT + (size_t)T * KD;          //  83,886,080
constexpr size_t KC_OUT = V_OUT + (size_t)T * KD;          // 100,663,296
constexpr size_t VC_OUT = KC_OUT + (size_t)NUM_SLOTS * KD; // 134,217,728

__device__ __forceinline__ void rope4(const float4& a, const float4& b,
                                      const float* cs, const float* sn, int j0,
                                      float4& o1, float4& o2) {
    o1.x = a.x * cs[j0 + 0] - b.x * sn[j0 + 0];
    o1.y = a.y * cs[j0 + 1] - b.y * sn[j0 + 1];
    o1.z = a.z * cs[j0 + 2] - b.z * sn[j0 + 2];
    o1.w = a.w * cs[j0 + 3] - b.w * sn[j0 + 3];
    o2.x = b.x * cs[j0 + 0] + a.x * sn[j0 + 0];
    o2.y = b.y * cs[j0 + 1] + a.y * sn[j0 + 1];
    o2.z = b.z * cs[j0 + 2] + a.z * sn[j0 + 2];
    o2.w = b.w * cs[j0 + 3] + a.w * sn[j0 + 3];
}

// Kernel A: mark which cache slots get scattered into this call.
__global__ __launch_bounds__(256) void mark_slots_kernel(
    const int* __restrict__ slot_mapping, int* __restrict__ mapped)
{
    const int i = blockIdx.x * 256 + threadIdx.x;
    if (i < T) mapped[slot_mapping[i]] = 1;
}

// Kernel B: for UNMAPPED slots, copy the old cache row into the output
// caches. Mapped rows are written by the main kernel (disjoint sets, so
// B and C can run in any order after A).
__global__ __launch_bounds__(256) void cache_fill_kernel(
    const float* __restrict__ k_cache, const float* __restrict__ v_cache,
    const int* __restrict__ mapped, float* __restrict__ out)
{
    const int slot = blockIdx.x;
    if (mapped[slot]) return;           // block-uniform branch
    const int tid = threadIdx.x;
    const size_t row = (size_t)slot * KD;
    const float4 kv = ((const float4*)(k_cache + row))[tid];
    const float4 vv = ((const float4*)(v_cache + row))[tid];
    ((float4*)(out + KC_OUT + row))[tid] = kv;
    ((float4*)(out + VC_OUT + row))[tid] = vv;
}

// Kernel C: per-token rope + outputs + scatter of mapped cache rows.
__global__ __launch_bounds__(256) void rope_kv_kernel(
    const float* __restrict__ q, const float* __restrict__ k,
    const float* __restrict__ v,
    const int* __restrict__ positions, const int* __restrict__ slot_mapping,
    float* __restrict__ out)
{
    const int tok = blockIdx.x;
    const int tid = threadIdx.x;

    __shared__ float cs[HALF];
    __shared__ float sn[HALF];

    const int pos  = positions[tok];
    const int slot = slot_mapping[tok];

    if (tid < HALF) {
        // inv_freq[j] = 10000^(-2j/128), computed in double for accuracy.
        const double inv = exp(-(double)(2 * tid) * (log(10000.0) / 128.0));
        const float freq = (float)((double)pos * inv);
        float s, c;
        sincosf(freq, &s, &c);
        cs[tid] = c;
        sn[tid] = s;
    }
    __syncthreads();

    // ---- Q rope: 32 heads x 16 pair-quads = 512 pair-quads ----
    {
        const float4* qrow = (const float4*)(q + (size_t)tok * QD);
        float4*       orow = (float4*)(out + Q_OUT + (size_t)tok * QD);
        #pragma unroll
        for (int i = 0; i < 2; ++i) {
            const int p    = i * 256 + tid;   // 0..511
            const int head = p >> 4;
            const int jq   = p & 15;
            const int j0   = jq * 4;
            const float4 a = qrow[head * 32 + jq];
            const float4 b = qrow[head * 32 + 16 + jq];
            float4 o1, o2;
            rope4(a, b, cs, sn, j0, o1, o2);
            orow[head * 32 + jq]      = o1;
            orow[head * 32 + 16 + jq] = o2;
        }
    }

    // ---- K rope + scatter into k_cache_new: 8 heads x 16 pair-quads = 128 ----
    if (tid < 128) {
        const int head = tid >> 4;
        const int jq   = tid & 15;
        const int j0   = jq * 4;
        const float4* krow = (const float4*)(k + (size_t)tok * KD);
        const float4 a = krow[head * 32 + jq];
        const float4 b = krow[head * 32 + 16 + jq];
        float4 o1, o2;
        rope4(a, b, cs, sn, j0, o1, o2);
        float4* korow = (float4*)(out + K_OUT + (size_t)tok * KD);
        korow[head * 32 + jq]      = o1;
        korow[head * 32 + 16 + jq] = o2;
        float4* kcrow = (float4*)(out + KC_OUT + (size_t)slot * KD);
        kcrow[head * 32 + jq]      = o1;
        kcrow[head * 32 + 16 + jq] = o2;
    }

    // ---- V passthrough + scatter into v_cache_new: 256 float4 ----
    {
        const float4* vrow = (const float4*)(v + (size_t)tok * KD);
        const float4 val = vrow[tid];
        ((float4*)(out + V_OUT  + (size_t)tok  * KD))[tid] = val;
        ((float4*)(out + VC_OUT + (size_t)slot * KD))[tid] = val;
    }
}

extern "C" void kernel_launch(void* const* d_in, const int* in_sizes, int n_in,
                              void* d_out, int out_size, void* d_ws, size_t ws_size,
                              hipStream_t stream) {
    const float* q   = (const float*)d_in[0];
    const float* k   = (const float*)d_in[1];
    const float* v   = (const float*)d_in[2];
    const int* positions    = (const int*)d_in[3];
    const int* slot_mapping = (const int*)d_in[4];
    const float* k_cache = (const float*)d_in[5];
    const float* v_cache = (const float*)d_in[6];
    float* out = (float*)d_out;
    int* mapped = (int*)d_ws;   // NUM_SLOTS ints = 128 KB

    // Clear the mapped flags every call (deterministic; ws not re-poisoned
    // between replays but we rebuild it fully each call).
    hipMemsetAsync(mapped, 0, (size_t)NUM_SLOTS * sizeof(int), stream);
    mark_slots_kernel<<<(T + 255) / 256, 256, 0, stream>>>(slot_mapping, mapped);
    cache_fill_kernel<<<NUM_SLOTS, 256, 0, stream>>>(k_cache, v_cache, mapped, out);
    rope_kv_kernel<<<T, 256, 0, stream>>>(q, k, v, positions, slot_mapping, out);
}

// Round 4
// 216.450 us; speedup vs baseline: 1.2833x; 1.1113x over previous
//
#include <hip/hip_runtime.h>
#include <math.h>

// Problem constants (match reference)
constexpr int NUM_HEADS    = 32;
constexpr int NUM_KV_HEADS = 8;
constexpr int HEAD_SIZE    = 128;
constexpr int T            = 16384;
constexpr int NUM_SLOTS    = 32768;
constexpr int QD = NUM_HEADS * HEAD_SIZE;     // 4096 floats per token
constexpr int KD = NUM_KV_HEADS * HEAD_SIZE;  // 1024 floats per token
constexpr int HALF = HEAD_SIZE / 2;           // 64

// Output layout (flat float offsets in d_out, reference return order)
constexpr size_t Q_OUT  = 0;
constexpr size_t K_OUT  = (size_t)T * QD;                  //  67,108,864
constexpr size_t V_OUT  = K_OUT + (size_t)T * KD;          //  83,886,080
constexpr size_t KC_OUT = V_OUT + (size_t)T * KD;          // 100,663,296
constexpr size_t VC_OUT = KC_OUT + (size_t)NUM_SLOTS * KD; // 134,217,728

// Native clang vector type — required by __builtin_nontemporal_*.
typedef float f4 __attribute__((ext_vector_type(4)));

__device__ __forceinline__ f4 ntload4(const float* p) {
    return __builtin_nontemporal_load((const f4*)p);
}
__device__ __forceinline__ void ntstore4(float* p, f4 v) {
    __builtin_nontemporal_store(v, (f4*)p);
}

__device__ __forceinline__ void rope4(const f4 a, const f4 b,
                                      const float* cs, const float* sn, int j0,
                                      f4& o1, f4& o2) {
    o1.x = a.x * cs[j0 + 0] - b.x * sn[j0 + 0];
    o1.y = a.y * cs[j0 + 1] - b.y * sn[j0 + 1];
    o1.z = a.z * cs[j0 + 2] - b.z * sn[j0 + 2];
    o1.w = a.w * cs[j0 + 3] - b.w * sn[j0 + 3];
    o2.x = b.x * cs[j0 + 0] + a.x * sn[j0 + 0];
    o2.y = b.y * cs[j0 + 1] + a.y * sn[j0 + 1];
    o2.z = b.z * cs[j0 + 2] + a.z * sn[j0 + 2];
    o2.w = b.w * cs[j0 + 3] + a.w * sn[j0 + 3];
}

// Kernel A: mark which cache slots get scattered into this call.
__global__ __launch_bounds__(256) void mark_slots_kernel(
    const int* __restrict__ slot_mapping, int* __restrict__ mapped)
{
    const int i = blockIdx.x * 256 + threadIdx.x;
    if (i < T) mapped[slot_mapping[i]] = 1;
}

// Kernel B (fused): blocks [0,T) do per-token rope + outputs + mapped-row
// scatter; blocks [T, T+NUM_SLOTS) copy unmapped cache rows. The two sets
// of cache-row writes are disjoint by construction of `mapped`.
__global__ __launch_bounds__(256) void fused_rope_fill_kernel(
    const float* __restrict__ q, const float* __restrict__ k,
    const float* __restrict__ v,
    const int* __restrict__ positions, const int* __restrict__ slot_mapping,
    const float* __restrict__ k_cache, const float* __restrict__ v_cache,
    const int* __restrict__ mapped, float* __restrict__ out)
{
    const int b   = blockIdx.x;
    const int tid = threadIdx.x;

    if (b >= T) {
        // ---- cache-fill path: copy old row for unmapped slots ----
        const int slot = b - T;
        if (mapped[slot]) return;       // block-uniform branch
        const size_t row = (size_t)slot * KD;
        const f4 kv = ntload4(k_cache + row + tid * 4);
        const f4 vv = ntload4(v_cache + row + tid * 4);
        ntstore4(out + KC_OUT + row + tid * 4, kv);
        ntstore4(out + VC_OUT + row + tid * 4, vv);
        return;
    }

    // ---- token path ----
    const int tok = b;

    __shared__ float cs[HALF];
    __shared__ float sn[HALF];

    const int pos  = positions[tok];
    const int slot = slot_mapping[tok];

    if (tid < HALF) {
        // inv_freq[j] = 10000^(-2j/128), computed in double for accuracy.
        const double inv = exp(-(double)(2 * tid) * (log(10000.0) / 128.0));
        const float freq = (float)((double)pos * inv);
        float s, c;
        sincosf(freq, &s, &c);
        cs[tid] = c;
        sn[tid] = s;
    }
    __syncthreads();

    // ---- Q rope: 32 heads x 16 pair-quads = 512 pair-quads ----
    {
        const float* qrow = q + (size_t)tok * QD;
        float*       orow = out + Q_OUT + (size_t)tok * QD;
        #pragma unroll
        for (int i = 0; i < 2; ++i) {
            const int p    = i * 256 + tid;   // 0..511
            const int head = p >> 4;
            const int jq   = p & 15;
            const int j0   = jq * 4;
            const f4 a  = ntload4(qrow + head * 128 + j0);
            const f4 bq = ntload4(qrow + head * 128 + 64 + j0);
            f4 o1, o2;
            rope4(a, bq, cs, sn, j0, o1, o2);
            ntstore4(orow + head * 128 + j0,      o1);
            ntstore4(orow + head * 128 + 64 + j0, o2);
        }
    }

    // ---- K rope + scatter into k_cache_new: 8 heads x 16 pair-quads ----
    if (tid < 128) {
        const int head = tid >> 4;
        const int jq   = tid & 15;
        const int j0   = jq * 4;
        const float* krow = k + (size_t)tok * KD;
        const f4 a  = ntload4(krow + head * 128 + j0);
        const f4 bk = ntload4(krow + head * 128 + 64 + j0);
        f4 o1, o2;
        rope4(a, bk, cs, sn, j0, o1, o2);
        float* korow = out + K_OUT + (size_t)tok * KD;
        ntstore4(korow + head * 128 + j0,      o1);
        ntstore4(korow + head * 128 + 64 + j0, o2);
        float* kcrow = out + KC_OUT + (size_t)slot * KD;
        ntstore4(kcrow + head * 128 + j0,      o1);
        ntstore4(kcrow + head * 128 + 64 + j0, o2);
    }

    // ---- V passthrough + scatter into v_cache_new: 256 float4 ----
    {
        const f4 val = ntload4(v + (size_t)tok * KD + tid * 4);
        ntstore4(out + V_OUT  + (size_t)tok  * KD + tid * 4, val);
        ntstore4(out + VC_OUT + (size_t)slot * KD + tid * 4, val);
    }
}

extern "C" void kernel_launch(void* const* d_in, const int* in_sizes, int n_in,
                              void* d_out, int out_size, void* d_ws, size_t ws_size,
                              hipStream_t stream) {
    const float* q   = (const float*)d_in[0];
    const float* k   = (const float*)d_in[1];
    const float* v   = (const float*)d_in[2];
    const int* positions    = (const int*)d_in[3];
    const int* slot_mapping = (const int*)d_in[4];
    const float* k_cache = (const float*)d_in[5];
    const float* v_cache = (const float*)d_in[6];
    float* out = (float*)d_out;
    int* mapped = (int*)d_ws;   // NUM_SLOTS ints = 128 KB

    (void)hipMemsetAsync(mapped, 0, (size_t)NUM_SLOTS * sizeof(int), stream);
    mark_slots_kernel<<<(T + 255) / 256, 256, 0, stream>>>(slot_mapping, mapped);
    fused_rope_fill_kernel<<<T + NUM_SLOTS, 256, 0, stream>>>(
        q, k, v, positions, slot_mapping, k_cache, v_cache, mapped, out);
}